// Round 7
// baseline (462.511 us; speedup 1.0000x reference)
//
#include <hip/hip_runtime.h>
#include <hip/hip_bf16.h>
#include <math.h>

#define NG 4
#define NN 50000
#define NE 800000
#define DD 64
#define CAP 64
#define NT 64           // nodes per block tile
#define NTILE 391       // tiles per (graph, half): 391*64 = 25024 >= 25000
#define NPASS 8         // dst-stripe passes per build slot
#define STRIPE (NN / 2 / NPASS)   // 3125 nodes per pass

typedef __attribute__((ext_vector_type(8))) short short8;
typedef __attribute__((ext_vector_type(4))) float float4v;

__device__ __forceinline__ unsigned short f2b(float f) {
    union { __hip_bfloat16 h; unsigned short u; } cv;
    cv.h = __float2bfloat16(f);
    return cv.u;
}
__device__ __forceinline__ float b2f(unsigned short u) {
    union { unsigned short u; __hip_bfloat16 h; } cv;
    cv.u = u;
    return __bfloat162float(cv.h);
}

// ---- init: detect int64 (bit0) + verify MFMA layout (bit1), one block ------
__global__ void init_kernel(const int* __restrict__ ei, int* __restrict__ flags) {
    __shared__ alignas(16) unsigned short A[16 * 32];
    __shared__ unsigned short B[32 * 16];
    int t = threadIdx.x;
    int any_nonzero = 0;
    for (int i = t; i < 128; i += 64) any_nonzero |= ei[2 * i + 1];
    unsigned long long nz = __ballot(any_nonzero != 0);
    int is64 = (nz == 0ULL) ? 1 : 0;
    for (int i = t; i < 512; i += 64) {
        int r = i >> 5, k = i & 31;
        A[i] = f2b((float)(((r * 5 + k * 3) & 31) - 15));
        int kk = i >> 4, c = i & 15;
        B[i] = f2b((float)(((kk * 7 + c * 11) & 31) - 15));
    }
    __syncthreads();
    short8 a = *(const short8*)&A[(t & 15) * 32 + (t >> 4) * 8];
    int c = t & 15, kb = (t >> 4) * 8;
    short8 b;
    for (int j = 0; j < 8; ++j) b[j] = (short)B[(kb + j) * 16 + c];
    float4v acc = {0.f, 0.f, 0.f, 0.f};
    acc = __builtin_amdgcn_mfma_f32_16x16x32_bf16(a, b, acc, 0, 0, 0);
    int ok = 1;
    for (int reg = 0; reg < 4; ++reg) {
        int row = (t >> 4) * 4 + reg;
        float ref = 0.f;
        for (int k = 0; k < 32; ++k)
            ref += (float)(((row * 5 + k * 3) & 31) - 15) *
                   (float)(((k * 7 + c * 11) & 31) - 15);
        if (acc[reg] != ref) ok = 0;
    }
    unsigned long long vote = __ballot(ok);
    if (t == 0) flags[0] = is64 | ((vote == ~0ULL) ? 2 : 0);
}

// nt (streaming) edge-index load
__device__ __forceinline__ int nt_idx(const int* __restrict__ ei, long pos, int is64) {
    return is64 ? __builtin_nontemporal_load(ei + 2 * pos)
                : __builtin_nontemporal_load(ei + pos);
}

// ---- bucket build: XCD-local + dst-stripe passes ----------------------------
// Slot s = blockIdx&7 -> XCD s, graph s>>1, dst half s&1. NPASS passes per
// slot; pass p admits dst in a 3125-node stripe -> dirty footprint ~400KB
// stays LRU-warm for the whole pass, each bucket line written back ~once
// (attacks the 6x write amplification seen in rounds 5/6). dst re-scan is
// L2/L3-served. CH=8 batching for load/atomic ILP.
__global__ void build_kernel(const int* __restrict__ ei, const int* __restrict__ flags,
                             int* __restrict__ cnt, unsigned short* __restrict__ bucket) {
    const int CH = 8;
    int is64 = flags[0] & 1;
    int s = blockIdx.x & 7;
    int g = s >> 1;
    int half_lo = (s & 1) * (NN / 2);
    int bsl = blockIdx.x >> 3;
    int nthreads = (gridDim.x >> 3) * blockDim.x;
    int tid = bsl * blockDim.x + threadIdx.x;
    long ebase = (long)g * 2 * NE;

    for (int p = 0; p < NPASS; ++p) {
        int plo = half_lo + p * STRIPE, phi = plo + STRIPE;
        for (int e0 = tid; e0 < NE; e0 += nthreads * CH) {
            int dstv[CH], srcv[CH];
            bool ok[CH];
#pragma unroll
            for (int j = 0; j < CH; ++j) {
                int e = e0 + j * nthreads;
                bool inb = e < NE;
                int ec = inb ? e : NE - 1;          // clamped: always-valid addr
                int d = nt_idx(ei, ebase + NE + ec, is64);
                dstv[j] = d;
                ok[j] = inb && d >= plo && d < phi;
            }
#pragma unroll
            for (int j = 0; j < CH; ++j) {
                int e = e0 + j * nthreads;
                int ec = e < NE ? e : NE - 1;
                // load src only when needed this pass (keeps stream smaller)
                srcv[j] = ok[j] ? nt_idx(ei, ebase + ec, is64) : 0;
            }
            int posv[CH];
#pragma unroll
            for (int j = 0; j < CH; ++j)
                posv[j] = ok[j] ? atomicAdd(&cnt[g * NN + dstv[j]], 1) : CAP;
#pragma unroll
            for (int j = 0; j < CH; ++j)
                if (posv[j] < CAP)
                    bucket[(long)(g * NN + dstv[j]) * CAP + posv[j]] = (unsigned short)srcv[j];
        }
    }
}

// ---- convert x f32 -> bf16 -------------------------------------------------
__global__ void convert_kernel(const float* __restrict__ x, unsigned short* __restrict__ xb) {
    long total = (long)NG * NN * DD / 4;
    long stride = (long)gridDim.x * blockDim.x;
    const float4* src = (const float4*)x;
    unsigned long long* dst = (unsigned long long*)xb;
    for (long i = (long)blockIdx.x * blockDim.x + threadIdx.x; i < total; i += stride) {
        float4 v = src[i];
        unsigned long long p = (unsigned long long)f2b(v.x)
                             | ((unsigned long long)f2b(v.y) << 16)
                             | ((unsigned long long)f2b(v.z) << 32)
                             | ((unsigned long long)f2b(v.w) << 48);
        dst[i] = p;
    }
}

// ---- fused gather + MFMA layer (unchanged from round 5) ---------------------
template <int LAYER>  // 0: out = h (bf16), 1: out = d_out (f32)
__launch_bounds__(256, 6)
__global__ void sage_mfma_kernel(const unsigned short* __restrict__ xin,
                                 const int* __restrict__ cnt,
                                 const unsigned short* __restrict__ bucket,
                                 const float* __restrict__ Wl, const float* __restrict__ Wr,
                                 const float* __restrict__ bias, void* __restrict__ outp,
                                 const int* __restrict__ flags) {
    if (!(flags[0] & 2)) return;
    __shared__ alignas(16) unsigned short sWT[2 * DD * DD];  // [m][col][k^swz] bf16, 16KB
    __shared__ alignas(16) unsigned short sM[NT * DD];       // [row][lane^swz] bf16, 8KB

    int s = blockIdx.x & 7, tb = blockIdx.x >> 3;
    int g = s >> 1;
    int tile = (s & 1) * NTILE + tb;      // halves match build partition
    int base = tile * NT;
    long gn0 = (long)g * NN;

    for (int i = threadIdx.x; i < 1024; i += 256) {
        int col = i & 63, ko = (i >> 6) & 7, m = i >> 9;
        const float* Wsrc = (m == 0 ? Wl : Wr) + (long)g * DD * DD;
        short8 t;
#pragma unroll
        for (int j = 0; j < 8; ++j)
            t[j] = (short)f2b(Wsrc[(ko * 8 + j) * DD + col]);
        *(short8*)&sWT[m * DD * DD + col * DD + ((ko * 8) ^ ((col & 7) << 3))] = t;
    }
    __syncthreads();

    int lane = threadIdx.x & 63;
    int w = threadIdx.x >> 6;

#pragma unroll 1
    for (int j = 0; j < 16; ++j) {
        int rl = w * 16 + j;
        int node = base + rl;
        float mean = 0.f;
        if (node < NN) {
            long row = gn0 + node;
            int ne = cnt[row];
            int nuse = ne < CAP ? ne : CAP;
            int msrc = (int)bucket[row * CAP + lane];
            float s0 = 0.f, s1 = 0.f, s2 = 0.f, s3 = 0.f;
            int e = 0;
            for (; e + 4 <= nuse; e += 4) {
                int a0 = __shfl(msrc, e), a1 = __shfl(msrc, e + 1);
                int a2 = __shfl(msrc, e + 2), a3 = __shfl(msrc, e + 3);
                s0 += b2f(xin[(gn0 + a0) * DD + lane]);
                s1 += b2f(xin[(gn0 + a1) * DD + lane]);
                s2 += b2f(xin[(gn0 + a2) * DD + lane]);
                s3 += b2f(xin[(gn0 + a3) * DD + lane]);
            }
            if (e < nuse) {
                int r = nuse - e;
                int a0 = __shfl(msrc, e);
                int a1 = __shfl(msrc, r > 1 ? e + 1 : e);
                int a2 = __shfl(msrc, r > 2 ? e + 2 : e);
                float v0 = b2f(xin[(gn0 + a0) * DD + lane]);
                float v1 = b2f(xin[(gn0 + a1) * DD + lane]);
                float v2 = b2f(xin[(gn0 + a2) * DD + lane]);
                s0 += v0;
                if (r > 1) s1 += v1;
                if (r > 2) s2 += v2;
            }
            mean = ((s0 + s1) + (s2 + s3)) / fmaxf((float)ne, 1.f);
        }
        sM[rl * DD + (lane ^ ((rl & 7) << 3))] = f2b(mean);
    }

    int arow = w * 16 + (lane & 15);
    int kb = (lane >> 4) * 8;
    int selfrow = base + arow; if (selfrow > NN - 1) selfrow = NN - 1;
    short8 am[2], ax[2];
#pragma unroll
    for (int ss = 0; ss < 2; ++ss) {
        int f0 = (kb + 32 * ss) ^ ((arow & 7) << 3);
        am[ss] = *(const short8*)&sM[arow * DD + f0];
        ax[ss] = *(const short8*)&xin[(gn0 + selfrow) * DD + kb + 32 * ss];
    }

    float4v acc[4];
#pragma unroll
    for (int c = 0; c < 4; ++c) {
        float b = bias[g * DD + c * 16 + (lane & 15)];
        acc[c] = {b, b, b, b};
    }
#pragma unroll
    for (int c = 0; c < 4; ++c) {
        int col = c * 16 + (lane & 15);
        int cswz = (col & 7) << 3;
#pragma unroll
        for (int ss = 0; ss < 2; ++ss) {
            short8 bl = *(const short8*)&sWT[0 * DD * DD + col * DD + ((kb + 32 * ss) ^ cswz)];
            acc[c] = __builtin_amdgcn_mfma_f32_16x16x32_bf16(am[ss], bl, acc[c], 0, 0, 0);
        }
#pragma unroll
        for (int ss = 0; ss < 2; ++ss) {
            short8 br = *(const short8*)&sWT[1 * DD * DD + col * DD + ((kb + 32 * ss) ^ cswz)];
            acc[c] = __builtin_amdgcn_mfma_f32_16x16x32_bf16(ax[ss], br, acc[c], 0, 0, 0);
        }
    }

    int q = lane >> 4, cl = lane & 15;
#pragma unroll
    for (int c = 0; c < 4; ++c) {
        int col = c * 16 + cl;
#pragma unroll
        for (int r = 0; r < 4; ++r) {
            int grow = base + w * 16 + q * 4 + r;
            if (grow >= NN) continue;
            float v = acc[c][r];
            v = v > 0.f ? v : expm1f(v);
            if (LAYER == 0)
                ((unsigned short*)outp)[(gn0 + grow) * DD + col] = f2b(v);
            else
                ((float*)outp)[(gn0 + grow) * DD + col] = v;
        }
    }
}

// ---- fallback (proven shfl-matvec), runs only if probe failed ---------------
template <int LAYER>
__global__ void fallback_kernel(const unsigned short* __restrict__ xin,
                                const int* __restrict__ cnt,
                                const unsigned short* __restrict__ bucket,
                                const float* __restrict__ Wl, const float* __restrict__ Wr,
                                const float* __restrict__ bias, void* __restrict__ outp,
                                const int* __restrict__ flags) {
    if (flags[0] & 2) return;
    __shared__ float sWl[DD * DD];
    __shared__ float sWr[DD * DD];
    __shared__ float sb[DD];
    int g = blockIdx.y;
    for (int i = threadIdx.x; i < DD * DD; i += blockDim.x) {
        sWl[i] = Wl[g * DD * DD + i];
        sWr[i] = Wr[g * DD * DD + i];
    }
    if (threadIdx.x < DD) sb[threadIdx.x] = bias[g * DD + threadIdx.x];
    __syncthreads();
    int lane = threadIdx.x & 63;
    int wpb = blockDim.x >> 6;
    long gn0 = (long)g * NN;
    for (int node = blockIdx.x * wpb + (threadIdx.x >> 6); node < NN;
         node += gridDim.x * wpb) {
        long row = gn0 + node;
        int ne = cnt[row];
        int nuse = ne < CAP ? ne : CAP;
        int msrc = (int)bucket[row * CAP + lane];
        float sum = 0.f;
        for (int e = 0; e < nuse; ++e) {
            int a0 = __shfl(msrc, e);
            sum += b2f(xin[(gn0 + a0) * DD + lane]);
        }
        float mean = sum / fmaxf((float)ne, 1.f);
        float self = b2f(xin[row * DD + lane]);
        float acc = sb[lane];
#pragma unroll
        for (int k = 0; k < DD; ++k) {
            float mk = __shfl(mean, k);
            float xk = __shfl(self, k);
            acc += mk * sWl[k * DD + lane] + xk * sWr[k * DD + lane];
        }
        acc = acc > 0.f ? acc : expm1f(acc);
        if (LAYER == 0) ((unsigned short*)outp)[row * DD + lane] = f2b(acc);
        else            ((float*)outp)[row * DD + lane] = acc;
    }
}

extern "C" void kernel_launch(void* const* d_in, const int* in_sizes, int n_in,
                              void* d_out, int out_size, void* d_ws, size_t ws_size,
                              hipStream_t stream) {
    const float* x   = (const float*)d_in[0];
    const int*   ei  = (const int*)d_in[1];
    const float* Wl1 = (const float*)d_in[2];
    const float* Wr1 = (const float*)d_in[3];
    const float* b1  = (const float*)d_in[4];
    const float* Wl2 = (const float*)d_in[5];
    const float* Wr2 = (const float*)d_in[6];
    const float* b2  = (const float*)d_in[7];
    float* out = (float*)d_out;

    // ws: cnt i32[200000] | bucket u16[200000*64] | h u16[200000*64] | flags i32
    // = 800000 + 25600000 + 25600000 + 4 = 52,000,004 B (proven budget)
    int* cnt = (int*)d_ws;
    unsigned short* bucket = (unsigned short*)(cnt + (size_t)NG * NN);
    unsigned short* h = bucket + (size_t)NG * NN * CAP;
    int* flags = (int*)(h + (size_t)NG * NN * DD);
    // xb (x as bf16, 25.6 MB) lives in d_out's first half; dead before layer 2
    unsigned short* xb = (unsigned short*)d_out;

    hipMemsetAsync(cnt, 0, (size_t)NG * NN * sizeof(int), stream);
    init_kernel<<<1, 64, 0, stream>>>(ei, flags);
    build_kernel<<<2048, 256, 0, stream>>>(ei, flags, cnt, bucket);
    convert_kernel<<<2048, 256, 0, stream>>>(x, xb);

    const int grid = NTILE * 8;  // 391 tb x 8 XCD slots
    dim3 fgrid(512, NG);
    // layer 1: xb -> h (bf16)
    sage_mfma_kernel<0><<<grid, 256, 0, stream>>>(xb, cnt, bucket, Wl1, Wr1, b1, h, flags);
    fallback_kernel<0><<<fgrid, 256, 0, stream>>>(xb, cnt, bucket, Wl1, Wr1, b1, h, flags);
    // layer 2: h -> out (f32)
    sage_mfma_kernel<1><<<grid, 256, 0, stream>>>(h, cnt, bucket, Wl2, Wr2, b2, out, flags);
    fallback_kernel<1><<<fgrid, 256, 0, stream>>>(h, cnt, bucket, Wl2, Wr2, b2, out, flags);
}